// Round 1
// baseline (701.201 us; speedup 1.0000x reference)
//
#include <hip/hip_runtime.h>
#include <cstddef>

// Problem constants (ST-GCN block)
#define N_  32
#define C_  64
#define T_  300
#define V_  25
#define M_  2
#define S_  3
#define O_  64
#define OS_ 192   // O*S
#define TT  4     // t-values per block

// LDS layout strides (floats) — chosen for bank-conflict freedom:
//  Ws stride 68: bank = (4o + c) % 32 -> 8 distinct-o lanes hit distinct/2-way banks
//  Ys stride 36: bank = (4o + v) % 32 -> distinct across the 8 o-groups of a wave
//  Xs/PAs stride 32: float4 reads indexed by tx*4 span all 32 banks
#define XS_STRIDE 32
#define WS_STRIDE 68
#define PAS_VSTR  32
#define PAS_SSTR  (V_ * PAS_VSTR)
#define YS_STRIDE 36

__global__ __launch_bounds__(512)
void stgcn_fused(const float* __restrict__ x,
                 const float* __restrict__ PA,
                 const float* __restrict__ Wc,
                 const float* __restrict__ cb,
                 const float* __restrict__ bn_g,
                 const float* __restrict__ bn_b,
                 const float* __restrict__ bn_m,
                 const float* __restrict__ bn_v,
                 float* __restrict__ out)
{
    __shared__ __align__(16) float Ws [OS_ * WS_STRIDE];  // 52.2 KB
    __shared__ __align__(16) float PAs[S_  * PAS_SSTR];   //  9.6 KB
    __shared__ __align__(16) float Xs [C_  * XS_STRIDE];  //  8.0 KB
    __shared__ __align__(16) float Ys [OS_ * YS_STRIDE];  // 27.6 KB

    const int tid = threadIdx.x;
    const int nb  = blockIdx.x;            // 0 .. N_*(T_/TT)-1
    const int n   = nb / (T_ / TT);
    const int t0  = (nb % (T_ / TT)) * TT;

    // ---- stage weights into LDS (once per block) ----
    for (int idx = tid; idx < OS_ * C_; idx += 512) {
        Ws[(idx >> 6) * WS_STRIDE + (idx & 63)] = Wc[idx];
    }
    for (int idx = tid; idx < S_ * V_ * V_; idx += 512) {
        const int s = idx / (V_ * V_);
        const int r = idx - s * (V_ * V_);
        const int v = r / V_;
        const int w = r - v * V_;
        PAs[s * PAS_SSTR + v * PAS_VSTR + w] = PA[idx];
    }

    const int tx = tid & 7;    // 4-wide v/w tile: v = tx*4+j
    const int ty = tid >> 3;   // 0..63

    // per-thread constants: stage-1 handles o_full = ty*3+i; stage-2 handles o = ty
    float cb3[3];
    #pragma unroll
    for (int i = 0; i < 3; ++i) cb3[i] = cb[ty * 3 + i];
    const float scl = bn_g[ty] * rsqrtf(bn_v[ty] + 1e-5f);
    const float sft = bn_b[ty] - bn_m[ty] * scl;

    for (int tt = 0; tt < TT; ++tt) {
        const int t = t0 + tt;
        for (int m = 0; m < M_; ++m) {
            // protects Xs/Ys from the previous iteration's readers,
            // and (first iter) makes Ws/PAs visible before stage 1
            __syncthreads();

            // ---- load X tile: x[n, c, t, v, m] for all c, v ----
            for (int idx = tid; idx < C_ * V_; idx += 512) {
                const int c = idx / V_;
                const int v = idx - c * V_;
                Xs[c * XS_STRIDE + v] =
                    x[((((size_t)n * C_ + c) * T_ + t) * V_ + v) * M_ + m];
            }
            __syncthreads();

            // ---- stage 1: Y[o_full, v] = sum_c W[o_full,c] * X[c,v] + cb ----
            float acc[3][4];
            #pragma unroll
            for (int i = 0; i < 3; ++i)
                #pragma unroll
                for (int j = 0; j < 4; ++j) acc[i][j] = cb3[i];

            #pragma unroll 4
            for (int c = 0; c < C_; ++c) {
                const float4 xv = *(const float4*)&Xs[c * XS_STRIDE + tx * 4];
                #pragma unroll
                for (int i = 0; i < 3; ++i) {
                    const float wv = Ws[(ty * 3 + i) * WS_STRIDE + c];
                    acc[i][0] = fmaf(wv, xv.x, acc[i][0]);
                    acc[i][1] = fmaf(wv, xv.y, acc[i][1]);
                    acc[i][2] = fmaf(wv, xv.z, acc[i][2]);
                    acc[i][3] = fmaf(wv, xv.w, acc[i][3]);
                }
            }
            #pragma unroll
            for (int i = 0; i < 3; ++i) {
                *(float4*)&Ys[(ty * 3 + i) * YS_STRIDE + tx * 4] =
                    make_float4(acc[i][0], acc[i][1], acc[i][2], acc[i][3]);
            }
            __syncthreads();

            // ---- stage 2: Z[o, w] = sum_s sum_v Y[s*O+o, v] * PA[s, v, w] ----
            float z0 = 0.f, z1 = 0.f, z2 = 0.f, z3 = 0.f;
            #pragma unroll
            for (int s = 0; s < S_; ++s) {
                #pragma unroll 5
                for (int v = 0; v < V_; ++v) {
                    const float  yv  = Ys[(s * O_ + ty) * YS_STRIDE + v];
                    const float4 pav =
                        *(const float4*)&PAs[s * PAS_SSTR + v * PAS_VSTR + tx * 4];
                    z0 = fmaf(yv, pav.x, z0);
                    z1 = fmaf(yv, pav.y, z1);
                    z2 = fmaf(yv, pav.z, z2);
                    z3 = fmaf(yv, pav.w, z3);
                }
            }

            // ---- epilogue: BN + ReLU + residual + ReLU, store ----
            const float4 res = *(const float4*)&Xs[ty * XS_STRIDE + tx * 4];
            const float zz[4] = {z0, z1, z2, z3};
            const float rr[4] = {res.x, res.y, res.z, res.w};
            const size_t obase =
                ((((size_t)n * O_ + ty) * T_ + t) * V_) * M_ + m;
            #pragma unroll
            for (int j = 0; j < 4; ++j) {
                const int w = tx * 4 + j;
                if (w < V_) {
                    float q = fmaf(zz[j], scl, sft);
                    q = fmaxf(q, 0.0f);
                    q = fmaxf(q + rr[j], 0.0f);
                    out[obase + (size_t)w * M_] = q;
                }
            }
        }
    }
}

extern "C" void kernel_launch(void* const* d_in, const int* in_sizes, int n_in,
                              void* d_out, int out_size, void* d_ws, size_t ws_size,
                              hipStream_t stream)
{
    const float* x    = (const float*)d_in[0];  // (32,64,300,25,2)
    const float* PA   = (const float*)d_in[1];  // (3,25,25)
    const float* Wc   = (const float*)d_in[2];  // (192,64)
    const float* cb   = (const float*)d_in[3];  // (192,)
    const float* bn_g = (const float*)d_in[4];  // (64,)
    const float* bn_b = (const float*)d_in[5];
    const float* bn_m = (const float*)d_in[6];
    const float* bn_v = (const float*)d_in[7];
    float* out = (float*)d_out;                 // (32,64,300,25,2)

    const int grid = N_ * (T_ / TT);            // 32 * 75 = 2400 blocks
    stgcn_fused<<<grid, 512, 0, stream>>>(x, PA, Wc, cb, bn_g, bn_b, bn_m, bn_v, out);
}

// Round 2
// 438.915 us; speedup vs baseline: 1.5976x; 1.5976x over previous
//
#include <hip/hip_runtime.h>
#include <cstddef>
#include <cstdint>

// ST-GCN block, MFMA restructure.
// Stage 1: Y[os=192][pos=64] = W·X + cb per (n,t), pos = m*32 + v (v padded 25->32)
// Stage 2: Z[o=64][w=32pad]  = sum_s Y_s · PA_s  (K = v = 32 padded, PA pads zeroed)
// Epilogue: BN + relu + residual + relu, scalar stores (residual hits L2-warm lines).
#define N_  32
#define C_  64
#define T_  300
#define V_  25
#define M_  2
#define S_  3
#define O_  64
#define OS_ 192
#define TB  10            // t-values per block
#define NT_BLK (T_/TB)    // 30 t-blocks per n
#define CTVM (C_*T_*V_*M_)   // 960000, per-n stride
#define TVM  (T_*V_*M_)      // 15000,  per-channel stride
#define VM   (V_*M_)         // 50,     per-t stride
#define XPITCH 72         // bf16 pitch: 144B rows -> 16B-aligned, 2-way banks
#define YPITCH 72

typedef short  short8  __attribute__((ext_vector_type(8)));
typedef float  float4_ __attribute__((ext_vector_type(4)));

__device__ __forceinline__ short f2bf(float f) {   // fp32 -> bf16 RNE
    uint32_t u = __float_as_uint(f);
    u += 0x7FFFu + ((u >> 16) & 1u);
    return (short)(u >> 16);
}

// ---- prep: W -> bf16 [os][c]; PA -> bf16 transposed+padded [s][w32][v32];
//      BN folded scale/shift. Runs every launch (graph-safe), ~15.4K threads.
__global__ void stgcn_prep(const float* __restrict__ Wc, const float* __restrict__ PA,
                           const float* __restrict__ g,  const float* __restrict__ b,
                           const float* __restrict__ mn, const float* __restrict__ vr,
                           short* __restrict__ Wb, short* __restrict__ PAb,
                           float* __restrict__ scl, float* __restrict__ sft)
{
    const int i = blockIdx.x * 256 + threadIdx.x;
    if (i < OS_ * C_) Wb[i] = f2bf(Wc[i]);
    const int r = i - OS_ * C_;
    if (r >= 0 && r < S_ * 32 * 32) {
        const int s = r >> 10, rem = r & 1023, wp = rem >> 5, vp = rem & 31;
        const float val = (wp < V_ && vp < V_) ? PA[s * V_ * V_ + vp * V_ + wp] : 0.0f;
        PAb[r] = f2bf(val);
    }
    const int q = r - S_ * 32 * 32;
    if (q >= 0 && q < O_) {
        const float sc = g[q] * rsqrtf(vr[q] + 1e-5f);
        scl[q] = sc;
        sft[q] = b[q] - mn[q] * sc;
    }
}

__global__ __launch_bounds__(256)
void stgcn_main(const float* __restrict__ x, const float* __restrict__ cb,
                const short* __restrict__ Wb, const short* __restrict__ PAb,
                const float* __restrict__ sclg, const float* __restrict__ sftg,
                float* __restrict__ out)
{
    __shared__ short Xb[64 * XPITCH];    //  9.2 KB: [pos][c] bf16
    __shared__ short Ys[OS_ * YPITCH];   // 27.6 KB: [os][pos] bf16
    __shared__ float sclS[O_], sftS[O_];

    const int tid  = threadIdx.x;
    const int wv   = tid >> 6;
    const int lane = tid & 63;
    const int quad = lane >> 4;
    const int l15  = lane & 15;

    const int n  = blockIdx.x / NT_BLK;
    const int t0 = (blockIdx.x % NT_BLK) * TB;
    const size_t xbase = (size_t)n * CTVM;

    // zero the v-pad rows of Xb once (pos 25..31, 57..63) — never rewritten,
    // so Y at pad cols = cb (finite) and stage-2 PA pads (=0) annihilate them.
    for (int i = tid; i < 14 * XPITCH; i += 256) {
        const int pr = i / XPITCH, cc = i - pr * XPITCH;
        const int pos = (pr < 7) ? (25 + pr) : (50 + pr);   // 25..31, 57..63
        Xb[pos * XPITCH + cc] = 0;
    }
    if (tid < O_) { sclS[tid] = sclg[tid]; sftS[tid] = sftg[tid]; }

    // ---- per-wave constant fragments (live across the whole t-loop) ----
    // stage 1: wave owns os rows [wv*48, wv*48+48)
    const int wbase = wv * 48;
    short8 aW[3][2];   // A[m=l15][k=quad*8+j], k-steps of 32 over c=64
    #pragma unroll
    for (int mt = 0; mt < 3; ++mt)
        #pragma unroll
        for (int ks = 0; ks < 2; ++ks)
            aW[mt][ks] = *(const short8*)(Wb + ((wbase + mt * 16 + l15) * C_ + ks * 32 + quad * 8));

    // stage 2: wave owns (m = wv>>1, w-half h = wv&1)
    const int m2 = wv >> 1, hh = wv & 1;
    short8 bP[3];      // B[k=v=quad*8+j][n=w=l15]
    #pragma unroll
    for (int s = 0; s < 3; ++s)
        bP[s] = *(const short8*)(PAb + (s * 1024 + (hh * 16 + l15) * 32 + quad * 8));

    float cbv[3][4];   // bias for stage-1 acc rows o = wbase + mt*16 + quad*4 + r
    #pragma unroll
    for (int mt = 0; mt < 3; ++mt)
        #pragma unroll
        for (int r = 0; r < 4; ++r)
            cbv[mt][r] = cb[wbase + mt * 16 + quad * 4 + r];

    for (int t = t0; t < t0 + TB; ++t) {
        __syncthreads();   // B0: prev iter's Xb/Ys readers done (1st: pads+scl visible)

        // ---- stage X tile: x[n,c,t,v,m] -> Xb[m*32+v][c] bf16 ----
        const float* xt = x + xbase + (size_t)t * VM;
        for (int i = tid; i < C_ * V_; i += 256) {
            const int c = i / V_, v = i - c * V_;
            const float2 xv = *(const float2*)(xt + (size_t)c * TVM + v * 2);
            Xb[v * XPITCH + c]        = f2bf(xv.x);   // m = 0
            Xb[(32 + v) * XPITCH + c] = f2bf(xv.y);   // m = 1
        }
        __syncthreads();   // B1

        // ---- stage 1: Y = W·X + cb  (12 16x16 tiles per wave, K=64) ----
        short8 bX[4][2];   // B[k=c][n=pos]
        #pragma unroll
        for (int nt = 0; nt < 4; ++nt)
            #pragma unroll
            for (int ks = 0; ks < 2; ++ks)
                bX[nt][ks] = *(const short8*)(Xb + (nt * 16 + l15) * XPITCH + ks * 32 + quad * 8);

        #pragma unroll
        for (int mt = 0; mt < 3; ++mt) {
            #pragma unroll
            for (int nt = 0; nt < 4; ++nt) {
                float4_ acc = { cbv[mt][0], cbv[mt][1], cbv[mt][2], cbv[mt][3] };
                acc = __builtin_amdgcn_mfma_f32_16x16x32_bf16(aW[mt][0], bX[nt][0], acc, 0, 0, 0);
                acc = __builtin_amdgcn_mfma_f32_16x16x32_bf16(aW[mt][1], bX[nt][1], acc, 0, 0, 0);
                // C/D: row = quad*4 + r (o), col = l15 (pos)
                #pragma unroll
                for (int r = 0; r < 4; ++r)
                    Ys[(wbase + mt * 16 + quad * 4 + r) * YPITCH + nt * 16 + l15] = f2bf(acc[r]);
            }
        }
        __syncthreads();   // B2: all 192 Ys rows written before any stage-2 read

        // ---- stage 2: Z[o][w] = sum_s Y_s[o][v] PA_s[v][w], K = 32 (v-pad) ----
        float4_ z[4];
        #pragma unroll
        for (int ot = 0; ot < 4; ++ot) { z[ot][0] = 0.f; z[ot][1] = 0.f; z[ot][2] = 0.f; z[ot][3] = 0.f; }
        #pragma unroll
        for (int s = 0; s < 3; ++s) {
            #pragma unroll
            for (int ot = 0; ot < 4; ++ot) {
                const short8 aY = *(const short8*)(Ys + (s * 64 + ot * 16 + l15) * YPITCH + m2 * 32 + quad * 8);
                z[ot] = __builtin_amdgcn_mfma_f32_16x16x32_bf16(aY, bP[s], z[ot], 0, 0, 0);
            }
        }

        // ---- epilogue: BN + relu + residual + relu ----
        const int wc = hh * 16 + l15;
        if (wc < V_) {
            #pragma unroll
            for (int ot = 0; ot < 4; ++ot) {
                #pragma unroll
                for (int r = 0; r < 4; ++r) {
                    const int o = ot * 16 + quad * 4 + r;
                    const size_t oi = xbase + (size_t)o * TVM + (size_t)t * VM + wc * 2 + m2;
                    float zz = z[ot][r] * sclS[o] + sftS[o];
                    zz = fmaxf(zz, 0.0f);
                    zz = fmaxf(zz + x[oi], 0.0f);   // residual: L2-warm from staging
                    out[oi] = zz;
                }
            }
        }
    }
}

extern "C" void kernel_launch(void* const* d_in, const int* in_sizes, int n_in,
                              void* d_out, int out_size, void* d_ws, size_t ws_size,
                              hipStream_t stream)
{
    const float* x    = (const float*)d_in[0];  // (32,64,300,25,2)
    const float* PA   = (const float*)d_in[1];  // (3,25,25)
    const float* Wc   = (const float*)d_in[2];  // (192,64)
    const float* cb   = (const float*)d_in[3];  // (192,)
    const float* bn_g = (const float*)d_in[4];
    const float* bn_b = (const float*)d_in[5];
    const float* bn_m = (const float*)d_in[6];
    const float* bn_v = (const float*)d_in[7];
    float* out = (float*)d_out;

    char* ws = (char*)d_ws;                     // 31.25 KB used
    short* Wb  = (short*)ws;                    // 12288 bf16
    short* PAb = (short*)(ws + 24576);          //  3072 bf16
    float* scl = (float*)(ws + 30720);          //    64 f32
    float* sft = (float*)(ws + 30976);          //    64 f32

    stgcn_prep<<<61, 256, 0, stream>>>(Wc, PA, bn_g, bn_b, bn_m, bn_v, Wb, PAb, scl, sft);
    stgcn_main<<<N_ * NT_BLK, 256, 0, stream>>>(x, cb, Wb, PAb, scl, sft, out);
}

// Round 4
// 289.479 us; speedup vs baseline: 2.4223x; 1.5162x over previous
//
#include <hip/hip_runtime.h>
#include <cstddef>
#include <cstdint>

// ST-GCN block, MFMA + software-pipelined staging.
// Stage 1 (swapped operands): Yt[pos=64][os=192] tiles -> stored as Ys[os][pos] via
//   packed b64 LDS writes. pos = m*32 + v (v padded 25->32, pad rows zeroed once).
// Stage 2: Z[o=64][w] = sum_s Y_s[o][v] PA_s[v][w], K=32 (PA pads zero).
// X staging double-buffered: global->reg prefetch for t+1 issued before stage 1 of t.
// Residual read from Xb (bf16) instead of global x.
#define N_  32
#define C_  64
#define T_  300
#define V_  25
#define M_  2
#define S_  3
#define O_  64
#define OS_ 192
#define TB  6             // t-values per block
#define NT_BLK (T_/TB)    // 50
#define CTVM (C_*T_*V_*M_)   // 960000
#define TVM  (T_*V_*M_)      // 15000
#define VM   (V_*M_)         // 50
#define XPITCH 72         // shorts; 144B rows
#define YPITCH 72

typedef short  short8  __attribute__((ext_vector_type(8)));
typedef float  float4_ __attribute__((ext_vector_type(4)));

__device__ __forceinline__ short f2bf(float f) {   // fp32 -> bf16 RNE
    uint32_t u = __float_as_uint(f);
    u += 0x7FFFu + ((u >> 16) & 1u);
    return (short)(u >> 16);
}
__device__ __forceinline__ unsigned pk2bf(float a, float b) {  // lo=a, hi=b
    const uint32_t ua = (uint32_t)(uint16_t)f2bf(a);
    const uint32_t ub = (uint32_t)(uint16_t)f2bf(b);
    return ua | (ub << 16);
}

// prep: W -> bf16 [os][c]; PA -> bf16 transposed+padded [s][w32][v32]; BN fold.
__global__ void stgcn_prep(const float* __restrict__ Wc, const float* __restrict__ PA,
                           const float* __restrict__ g,  const float* __restrict__ b,
                           const float* __restrict__ mn, const float* __restrict__ vr,
                           short* __restrict__ Wb, short* __restrict__ PAb,
                           float* __restrict__ scl, float* __restrict__ sft)
{
    const int i = blockIdx.x * 256 + threadIdx.x;
    if (i < OS_ * C_) Wb[i] = f2bf(Wc[i]);
    const int r = i - OS_ * C_;
    if (r >= 0 && r < S_ * 32 * 32) {
        const int s = r >> 10, rem = r & 1023, wp = rem >> 5, vp = rem & 31;
        const float val = (wp < V_ && vp < V_) ? PA[s * V_ * V_ + vp * V_ + wp] : 0.0f;
        PAb[r] = f2bf(val);
    }
    const int q = r - S_ * 32 * 32;
    if (q >= 0 && q < O_) {
        const float sc = g[q] * rsqrtf(vr[q] + 1e-5f);
        scl[q] = sc;
        sft[q] = b[q] - mn[q] * sc;
    }
}

__global__ __launch_bounds__(256, 3)
void stgcn_main(const float* __restrict__ x, const float* __restrict__ cb,
                const short* __restrict__ Wb, const short* __restrict__ PAb,
                const float* __restrict__ sclg, const float* __restrict__ sftg,
                float* __restrict__ out)
{
    __shared__ short Xb[2][64 * XPITCH];   // 18.4 KB (double-buffered)
    __shared__ short Ys[OS_ * YPITCH];     // 27.6 KB
    __shared__ float sclS[O_], sftS[O_];

    const int tid  = threadIdx.x;
    const int wv   = tid >> 6;
    const int lane = tid & 63;
    const int quad = lane >> 4;
    const int l15  = lane & 15;

    const int n  = blockIdx.x / NT_BLK;
    const int t0 = (blockIdx.x % NT_BLK) * TB;
    const size_t xbase = (size_t)n * CTVM;

    // zero v-pad rows (pos 25..31, 57..63) of BOTH X buffers, once
    for (int i = tid; i < 2 * 14 * XPITCH; i += 256) {
        const int bf = i / (14 * XPITCH);
        const int r  = i - bf * (14 * XPITCH);
        const int pr = r / XPITCH, cc = r - pr * XPITCH;
        const int pos = (pr < 7) ? (25 + pr) : (50 + pr);
        Xb[bf][pos * XPITCH + cc] = 0;
    }
    if (tid < O_) { sclS[tid] = sclg[tid]; sftS[tid] = sftg[tid]; }

    // ---- wave-constant fragments ----
    const int wbase = wv * 48;            // stage-1: this wave's 48 os rows
    short8 aW[3][2];                      // B-operand: B[k=c][n=os]
    #pragma unroll
    for (int mt = 0; mt < 3; ++mt)
        #pragma unroll
        for (int ks = 0; ks < 2; ++ks)
            aW[mt][ks] = *(const short8*)(Wb + (wbase + mt * 16 + l15) * C_ + ks * 32 + quad * 8);

    const int m2 = wv >> 1, hh = wv & 1;  // stage-2: wave owns (m, w-half)
    short8 bP[3];                         // B[k=v][n=w]
    #pragma unroll
    for (int s = 0; s < 3; ++s)
        bP[s] = *(const short8*)(PAb + (s * 1024 + (hh * 16 + l15) * 32 + quad * 8));

    float cbw[3];                         // stage-1 bias: per COLUMN (os = l15-mapped)
    #pragma unroll
    for (int mt = 0; mt < 3; ++mt) cbw[mt] = cb[wbase + mt * 16 + l15];

    // ---- prologue: stage t0 into Xb[0] ----
    {
        const float* xt = x + xbase + (size_t)t0 * VM;
        #pragma unroll
        for (int k = 0; k < 4; ++k) {
            const int p = tid + k * 256;           // 800 (cpair, v) pairs
            if (p < 800) {
                const int v = p % 25, cp = p / 25;
                const float2 f0 = *(const float2*)(xt + (size_t)(2 * cp)     * TVM + v * 2);
                const float2 f1 = *(const float2*)(xt + (size_t)(2 * cp + 1) * TVM + v * 2);
                ((unsigned*)Xb[0])[v * 36 + cp]        = pk2bf(f0.x, f1.x);  // m=0
                ((unsigned*)Xb[0])[(32 + v) * 36 + cp] = pk2bf(f0.y, f1.y);  // m=1
            }
        }
    }

    int cur = 0;
    for (int tt = 0; tt < TB; ++tt) {
        __syncthreads();   // B0: Xb[cur] staged; Ys free for rewrite

        // ---- issue prefetch loads for t+1 (consumed at iteration end) ----
        float2 R0[4], R1[4];
        const bool pf = (tt + 1 < TB);
        if (pf) {
            const float* xt = x + xbase + (size_t)(t0 + tt + 1) * VM;
            #pragma unroll
            for (int k = 0; k < 4; ++k) {
                const int p = tid + k * 256;
                if (p < 800) {
                    const int v = p % 25, cp = p / 25;
                    R0[k] = *(const float2*)(xt + (size_t)(2 * cp)     * TVM + v * 2);
                    R1[k] = *(const float2*)(xt + (size_t)(2 * cp + 1) * TVM + v * 2);
                }
            }
        }

        // ---- stage 1: D[pos][os] = X^T·W^T + cb  (A=X-frag, B=W-frag) ----
        const short* Xc = Xb[cur];
        short8 bX[4][2];                  // A[m=pos][k=c]
        #pragma unroll
        for (int nt = 0; nt < 4; ++nt)
            #pragma unroll
            for (int ks = 0; ks < 2; ++ks)
                bX[nt][ks] = *(const short8*)(Xc + (nt * 16 + l15) * XPITCH + ks * 32 + quad * 8);

        #pragma unroll
        for (int mt = 0; mt < 3; ++mt) {
            #pragma unroll
            for (int nt = 0; nt < 4; ++nt) {
                float4_ acc = { cbw[mt], cbw[mt], cbw[mt], cbw[mt] };
                acc = __builtin_amdgcn_mfma_f32_16x16x32_bf16(bX[nt][0], aW[mt][0], acc, 0, 0, 0);
                acc = __builtin_amdgcn_mfma_f32_16x16x32_bf16(bX[nt][1], aW[mt][1], acc, 0, 0, 0);
                // D: row = pos = nt*16 + quad*4 + r, col = os = wbase + mt*16 + l15
                const int os = wbase + mt * 16 + l15;
                *(uint2*)(Ys + os * YPITCH + nt * 16 + quad * 4) =
                    make_uint2(pk2bf(acc[0], acc[1]), pk2bf(acc[2], acc[3]));
            }
        }
        __syncthreads();   // B1: Ys complete

        // ---- stage 2: Z[o][w] = sum_s Y_s[o][v] PA_s[v][w] ----
        float4_ z[4];
        #pragma unroll
        for (int ot = 0; ot < 4; ++ot) { z[ot][0]=0.f; z[ot][1]=0.f; z[ot][2]=0.f; z[ot][3]=0.f; }
        #pragma unroll
        for (int s = 0; s < 3; ++s) {
            #pragma unroll
            for (int ot = 0; ot < 4; ++ot) {
                const short8 aY = *(const short8*)(Ys + (s * 64 + ot * 16 + l15) * YPITCH + m2 * 32 + quad * 8);
                z[ot] = __builtin_amdgcn_mfma_f32_16x16x32_bf16(aY, bP[s], z[ot], 0, 0, 0);
            }
        }

        // ---- epilogue: BN + relu + residual(from LDS, bf16) + relu ----
        const int wc = hh * 16 + l15;
        const int t  = t0 + tt;
        if (wc < V_) {
            const int xrow = (m2 * 32 + wc) * XPITCH;
            #pragma unroll
            for (int ot = 0; ot < 4; ++ot) {
                #pragma unroll
                for (int r = 0; r < 4; ++r) {
                    const int o = ot * 16 + quad * 4 + r;
                    const float res = __uint_as_float(((unsigned)(unsigned short)Xc[xrow + o]) << 16);
                    float q = fmaf(z[ot][r], sclS[o], sftS[o]);
                    q = fmaxf(q, 0.0f);
                    q = fmaxf(q + res, 0.0f);
                    out[xbase + (size_t)o * TVM + (size_t)t * VM + wc * 2 + m2] = q;
                }
            }
        }

        // ---- convert prefetched regs into the other X buffer ----
        if (pf) {
            short* Xn = Xb[cur ^ 1];
            #pragma unroll
            for (int k = 0; k < 4; ++k) {
                const int p = tid + k * 256;
                if (p < 800) {
                    const int v = p % 25, cp = p / 25;
                    ((unsigned*)Xn)[v * 36 + cp]        = pk2bf(R0[k].x, R1[k].x);
                    ((unsigned*)Xn)[(32 + v) * 36 + cp] = pk2bf(R0[k].y, R1[k].y);
                }
            }
        }
        cur ^= 1;
    }
}

extern "C" void kernel_launch(void* const* d_in, const int* in_sizes, int n_in,
                              void* d_out, int out_size, void* d_ws, size_t ws_size,
                              hipStream_t stream)
{
    const float* x    = (const float*)d_in[0];  // (32,64,300,25,2)
    const float* PA   = (const float*)d_in[1];  // (3,25,25)
    const float* Wc   = (const float*)d_in[2];  // (192,64)
    const float* cb   = (const float*)d_in[3];  // (192,)
    const float* bn_g = (const float*)d_in[4];
    const float* bn_b = (const float*)d_in[5];
    const float* bn_m = (const float*)d_in[6];
    const float* bn_v = (const float*)d_in[7];
    float* out = (float*)d_out;

    char* ws = (char*)d_ws;
    short* Wb  = (short*)ws;                    // 12288 bf16
    short* PAb = (short*)(ws + 24576);          //  3072 bf16
    float* scl = (float*)(ws + 30720);          //    64 f32
    float* sft = (float*)(ws + 30976);          //    64 f32

    stgcn_prep<<<61, 256, 0, stream>>>(Wc, PA, bn_g, bn_b, bn_m, bn_v, Wb, PAb, scl, sft);
    stgcn_main<<<N_ * NT_BLK, 256, 0, stream>>>(x, cb, Wb, PAb, scl, sft, out);
}